// Round 15
// baseline (162.181 us; speedup 1.0000x reference)
//
#include <hip/hip_runtime.h>
#include <hip/hip_bf16.h>

#define NRAYS 8192
#define SAMP  128
#define DVD   27
#define NFEAT 15

typedef float  f32x4  __attribute__((ext_vector_type(4)));
typedef float  f2     __attribute__((ext_vector_type(2)));
typedef short  short8 __attribute__((ext_vector_type(8)));

// fp32 -> bf16 (round-half-up), single value: 1 add + ds_write_b16_d16_hi
static __device__ __forceinline__ void stbf(short* p, float x) {
    union { unsigned u; struct { short lo, hi; } s; } v;
    v.u = __float_as_uint(x) + 0x8000u;
    *p = v.s.hi;
}
// two fp32 -> packed bf16x2 dword: 2 add + 1 v_perm
static __device__ __forceinline__ unsigned pack2bf(float a, float b) {
    const unsigned ua = __float_as_uint(a) + 0x8000u;
    const unsigned ub = __float_as_uint(b) + 0x8000u;
    return __builtin_amdgcn_perm(ub, ua, 0x07060302u);
}
static __device__ __forceinline__ float bf2f(short s) {
    return __uint_as_float(((unsigned)(unsigned short)s) << 16);
}
static __device__ __forceinline__ f2 max2z(f2 a) {
    return __builtin_elementwise_max(a, (f2){0.0f, 0.0f});
}
static __device__ __forceinline__ void sincos_fast(float x, float* s, float* c) {
    float r = x * 0.15915494309189535f;
    r = r - floorf(r);
    *s = __builtin_amdgcn_sinf(r);
    *c = __builtin_amdgcn_cosf(r);
}
static __device__ __forceinline__ float sin_fast(float x) {
    float r = x * 0.15915494309189535f;
    r = r - floorf(r);
    return __builtin_amdgcn_sinf(r);
}
static __device__ __forceinline__ float cos_fast(float x) {
    float r = x * 0.15915494309189535f;
    r = r - floorf(r);
    return __builtin_amdgcn_cosf(r);
}

// LDS layout (overlay) — R14 footprint (32208 B, 5 blk/CU):
//  staging (pre-b2): sW1t@0 [64*72]s, sW2t@9216 [16*72]s,
//                    sV1t@11520 [64*32]s (rows shifted +1; row0=0), sV2t@15616 [3*72]s
//  sGv@16384 [4][64]f (gap 16048..18432; per-wave, used between b1 and b2)
//  working (post-b2): sE@0 [4][32*72]s, sG@18432 [4][32*32]s
//  persistent: sOm@26624 [4][128]f, sRgb@28672 [4][384]s,
//              sVde@31744 [4][28]f, sRed@32192 [4]f
#define SMEM_BYTES 32208

__global__ void __launch_bounds__(256)
march_kernel(const float* __restrict__ orig,
             const float* __restrict__ dirs,
             const float* __restrict__ tmin,
             const float* __restrict__ tmax,
             const float* __restrict__ W1,
             const float* __restrict__ b1,
             const float* __restrict__ W2,
             const float* __restrict__ b2,
             const float* __restrict__ V1,
             const float* __restrict__ c1,
             const float* __restrict__ V2,
             const float* __restrict__ c2,
             float* __restrict__ out) {
    __shared__ __align__(16) char smem[SMEM_BYTES];
    short* const sW1t = (short*)(smem);
    short* const sW2t = (short*)(smem + 9216);
    short* const sV1t = (short*)(smem + 11520);
    short* const sV2t = (short*)(smem + 15616);
    float* const sGv  = (float*)(smem + 16384);
    short* const sEa  = (short*)(smem);
    short* const sGa  = (short*)(smem + 18432);
    float* const sOm  = (float*)(smem + 26624);
    short* const sRgb = (short*)(smem + 28672);
    float* const sVde = (float*)(smem + 31744);
    float* const sRed = (float*)(smem + 32192);

    const int tid  = threadIdx.x;
    const int lane = tid & 63;
    const int wave = tid >> 6;
    const int ray  = blockIdx.x * 4 + wave;

    // ---- block-redundant dt partial: sum(tmax - tmin) ----
    {
        const float4* tm0 = (const float4*)tmin;
        const float4* tm1 = (const float4*)tmax;
        float s = 0.0f;
        #pragma unroll
        for (int it = 0; it < 8; it++) {
            const int i = tid + it * 256;
            const float4 a = tm1[i], b = tm0[i];
            s += (a.x - b.x) + (a.y - b.y) + (a.z - b.z) + (a.w - b.w);
        }
        #pragma unroll
        for (int off = 32; off > 0; off >>= 1)
            s += __shfl_xor(s, off, 64);
        if (lane == 0) sRed[wave] = s;
    }

    // ---- cooperative weight staging ----
    for (int i = tid; i < 63 * 64; i += 256) {   // W1 [63][64]
        const int k = i >> 6, n = i & 63;
        stbf(&sW1t[n * 72 + k], W1[i]);
    }
    for (int i = tid; i < 64; i += 256) sW1t[i * 72 + 63] = 0;
    for (int i = tid; i < 64 * 16; i += 256) {   // W2 [64][16]
        const int k = i >> 4, n = i & 15;
        stbf(&sW2t[n * 72 + k], W2[i]);
    }
    for (int i = tid; i < 15 * 64; i += 256) {   // V1 rows 0..14 -> k slots 1..15
        const int k = i >> 6, n = i & 63;
        stbf(&sV1t[n * 32 + (k + 1)], V1[i]);
    }
    for (int i = tid; i < 64 * 17; i += 256) {   // zero k=0 and k=16..31
        const int n = i / 17, kk = i - 17 * n;
        const int k = (kk == 0) ? 0 : (15 + kk);
        sV1t[n * 32 + k] = 0;
    }
    for (int i = tid; i < 192; i += 256) {       // V2 [64][3]
        const int k = i / 3, n = i - 3 * k;
        stbf(&sV2t[n * 72 + k], V2[i]);
    }

    // ---- per-ray scalars ----
    const float ox = orig[ray * 3 + 0];
    const float oy = orig[ray * 3 + 1];
    const float oz = orig[ray * 3 + 2];
    const float dx = dirs[ray * 3 + 0];
    const float dy = dirs[ray * 3 + 1];
    const float dz = dirs[ray * 3 + 2];
    const float t0v = tmin[ray];
    const float trange = tmax[ray] - t0v;

    // ---- view-dir encoding (fp32) -> sVde (per-wave) ----
    {
        const float nrm = sqrtf(dx * dx + dy * dy + dz * dz);
        const float inv = 1.0f / (nrm + 1e-8f);
        const float vx = dx * inv, vy = dy * inv, vz = dz * inv;
        if (lane < DVD) {
            float val;
            if (lane < 3) {
                val = (lane == 0) ? vx : ((lane == 1) ? vy : vz);
            } else {
                const int q = lane - 3;
                const int b = q / 6;
                const int r = q - 6 * b;
                const bool isSin = (r < 3);
                const int d = isSin ? r : (r - 3);
                const float comp = (d == 0) ? vx : ((d == 1) ? vy : vz);
                const float a = (float)(1 << b) * comp;
                val = isSin ? sin_fast(a) : cos_fast(a);
            }
            sVde[wave * 28 + lane] = val;
        }
    }
    __syncthreads();   // barrier 1: staging + dt reduce complete

    const float dtv = (sRed[0] + sRed[1] + sRed[2] + sRed[3]) *
                      (1.0f / ((float)NRAYS * (float)SAMP));

    const int nfr  = lane & 15;
    const int quad = lane >> 4;

    // ---- B-fragments (addressing identical for A/B roles) ----
    short8 w1f[4][2], w2f[2], v1f[4], v2f[2];
    #pragma unroll
    for (int nt = 0; nt < 4; nt++)
        #pragma unroll
        for (int kt = 0; kt < 2; kt++)
            w1f[nt][kt] = *(const short8*)&sW1t[(nfr + 16 * nt) * 72 + quad * 8 + kt * 32];
    #pragma unroll
    for (int kt = 0; kt < 2; kt++)
        w2f[kt] = *(const short8*)&sW2t[nfr * 72 + quad * 8 + kt * 32];
    #pragma unroll
    for (int nt = 0; nt < 4; nt++)
        v1f[nt] = *(const short8*)&sV1t[(nfr + 16 * nt) * 32 + quad * 8];
    #pragma unroll
    for (int kt = 0; kt < 2; kt++) {
        if (nfr < 3)
            v2f[kt] = *(const short8*)&sV2t[nfr * 72 + quad * 8 + kt * 32];
        else
            v2f[kt] = (short8){0, 0, 0, 0, 0, 0, 0, 0};
    }

    // ---- row-major biases for the swapped layouts ----
    float4 b1q[4];
    #pragma unroll
    for (int nt = 0; nt < 4; nt++)
        b1q[nt] = *(const float4*)&b1[16 * nt + 4 * quad];
    const float4 b2q = *(const float4*)&b2[4 * quad];
    const float c20 = c2[0], c21 = c2[1], c22 = c2[2];

    // ---- gacc = c1 + vde@V1[15:42] ; redistribute to row-pairs via LDS ----
    {
        float gvv[4] = {0.0f, 0.0f, 0.0f, 0.0f};
        #pragma unroll 1
        for (int q = 0; q < DVD; q++) {
            const float e = sVde[wave * 28 + q];
            const float* vrow = V1 + (NFEAT + q) * 64;
            #pragma unroll
            for (int nt = 0; nt < 4; nt++) gvv[nt] += e * vrow[nfr + 16 * nt];
        }
        #pragma unroll
        for (int nt = 0; nt < 4; nt++)
            sGv[wave * 64 + nfr + 16 * nt] = gvv[nt] + c1[nfr + 16 * nt];
    }
    f2 ga[4][2];
    #pragma unroll
    for (int nt = 0; nt < 4; nt++) {
        const float* base = &sGv[wave * 64 + 16 * nt + 4 * quad];
        ga[nt][0] = *(const f2*)base;
        ga[nt][1] = *(const f2*)(base + 2);
    }
    __syncthreads();   // barrier 2: staging reads done -> working region free

    short* const myE = sEa + wave * (32 * 72);
    short* const myG = sGa + wave * (32 * 32);
    {
        int* gz = (int*)myG;
        for (int i = lane; i < 32 * 16; i += 64) gz[i] = 0;
    }

    const int sl   = lane >> 1;
    const int half = lane & 1;

    #pragma unroll 1
    for (int qq = 0; qq < 4; qq++) {
        // --- positional encodings (unchanged) ---
        {
            const int s = qq * 32 + sl;
            const float t = t0v + (float)s * (1.0f / 127.0f) * trange;
            const float px = ox + dx * t, py = oy + dy * t, pz = oz + dz * t;
            short* Erow = &myE[sl * 72];
            if (half == 0) {
                stbf(&Erow[0], px); stbf(&Erow[1], py); stbf(&Erow[2], pz);
                #pragma unroll 1
                for (int b = 0; b < 5; b++) {
                    const float f = (float)(1 << b);
                    float sx, cx, sy, cy, sz, cz;
                    sincos_fast(f * px, &sx, &cx);
                    sincos_fast(f * py, &sy, &cy);
                    sincos_fast(f * pz, &sz, &cz);
                    stbf(&Erow[3 + 6 * b + 0], sx);
                    stbf(&Erow[3 + 6 * b + 1], sy);
                    stbf(&Erow[3 + 6 * b + 2], sz);
                    stbf(&Erow[3 + 6 * b + 3], cx);
                    stbf(&Erow[3 + 6 * b + 4], cy);
                    stbf(&Erow[3 + 6 * b + 5], cz);
                }
            } else {
                #pragma unroll 1
                for (int b = 5; b < 10; b++) {
                    const float f = (float)(1 << b);
                    float sx, cx, sy, cy, sz, cz;
                    sincos_fast(f * px, &sx, &cx);
                    sincos_fast(f * py, &sy, &cy);
                    sincos_fast(f * pz, &sz, &cz);
                    stbf(&Erow[3 + 6 * b + 0], sx);
                    stbf(&Erow[3 + 6 * b + 1], sy);
                    stbf(&Erow[3 + 6 * b + 2], sz);
                    stbf(&Erow[3 + 6 * b + 3], cx);
                    stbf(&Erow[3 + 6 * b + 4], cy);
                    stbf(&Erow[3 + 6 * b + 5], cz);
                }
                Erow[63] = 0;
            }
        }
        // --- GEMM1: h^T = W1^T(A) x E(B); lane: rows 4q+r+16nt, col nfr+16mt ---
        f32x4 acc1[4][2];
        #pragma unroll
        for (int nt = 0; nt < 4; nt++)
            #pragma unroll
            for (int mt = 0; mt < 2; mt++)
                acc1[nt][mt] = (f32x4){0.0f, 0.0f, 0.0f, 0.0f};
        {
            short8 af[2][2];
            #pragma unroll
            for (int mt = 0; mt < 2; mt++)
                #pragma unroll
                for (int kt = 0; kt < 2; kt++)
                    af[mt][kt] = *(const short8*)&myE[(nfr + 16 * mt) * 72 + quad * 8 + kt * 32];
            #pragma unroll
            for (int nt = 0; nt < 4; nt++)
                #pragma unroll
                for (int mt = 0; mt < 2; mt++)
                    #pragma unroll
                    for (int kt = 0; kt < 2; kt++)
                        acc1[nt][mt] = __builtin_amdgcn_mfma_f32_16x16x32_bf16(
                            w1f[nt][kt], af[mt][kt], acc1[nt][mt], 0, 0, 0);
        }
        #pragma unroll
        for (int nt = 0; nt < 4; nt++) {
            const f2 b01 = {b1q[nt].x, b1q[nt].y};
            const f2 b23 = {b1q[nt].z, b1q[nt].w};
            #pragma unroll
            for (int mt = 0; mt < 2; mt++) {
                const f2 p0 = max2z((f2){acc1[nt][mt][0], acc1[nt][mt][1]} + b01);
                const f2 p1 = max2z((f2){acc1[nt][mt][2], acc1[nt][mt][3]} + b23);
                uint2 d;
                d.x = pack2bf(p0.x, p0.y);
                d.y = pack2bf(p1.x, p1.y);
                *(uint2*)&myE[(nfr + 16 * mt) * 72 + 16 * nt + 4 * quad] = d;
            }
        }
        // --- GEMM2: O^T = W2^T(A) x h(B); rows 4q+r (outs), col nfr+16mt ---
        f32x4 acc2[2];
        acc2[0] = (f32x4){0.0f, 0.0f, 0.0f, 0.0f};
        acc2[1] = (f32x4){0.0f, 0.0f, 0.0f, 0.0f};
        {
            short8 ah[2][2];
            #pragma unroll
            for (int mt = 0; mt < 2; mt++)
                #pragma unroll
                for (int kt = 0; kt < 2; kt++)
                    ah[mt][kt] = *(const short8*)&myE[(nfr + 16 * mt) * 72 + quad * 8 + kt * 32];
            #pragma unroll
            for (int mt = 0; mt < 2; mt++)
                #pragma unroll
                for (int kt = 0; kt < 2; kt++)
                    acc2[mt] = __builtin_amdgcn_mfma_f32_16x16x32_bf16(
                        w2f[kt], ah[mt][kt], acc2[mt], 0, 0, 0);
        }
        #pragma unroll
        for (int mt = 0; mt < 2; mt++) {
            const f2 q0 = (f2){acc2[mt][0], acc2[mt][1]} + (f2){b2q.x, b2q.y};
            const f2 q1 = (f2){acc2[mt][2], acc2[mt][3]} + (f2){b2q.z, b2q.w};
            uint2 d;
            d.x = pack2bf(q0.x, q0.y);
            d.y = pack2bf(q1.x, q1.y);
            *(uint2*)&myG[(nfr + 16 * mt) * 32 + 4 * quad] = d;
            if (quad == 0) {
                const float sg = fmaxf(q0.x, 0.0f);   // out0 + b2[0]
                sOm[wave * 128 + qq * 32 + nfr + 16 * mt] = __expf(-sg * dtv);
            }
        }
        // --- GEMM3: g^T = V1^T(A) x G(B) ---
        f32x4 acc3[4][2];
        #pragma unroll
        for (int nt = 0; nt < 4; nt++)
            #pragma unroll
            for (int mt = 0; mt < 2; mt++)
                acc3[nt][mt] = (f32x4){0.0f, 0.0f, 0.0f, 0.0f};
        {
            short8 ag[2];
            #pragma unroll
            for (int mt = 0; mt < 2; mt++)
                ag[mt] = *(const short8*)&myG[(nfr + 16 * mt) * 32 + quad * 8];
            #pragma unroll
            for (int nt = 0; nt < 4; nt++)
                #pragma unroll
                for (int mt = 0; mt < 2; mt++)
                    acc3[nt][mt] = __builtin_amdgcn_mfma_f32_16x16x32_bf16(
                        v1f[nt], ag[mt], acc3[nt][mt], 0, 0, 0);
        }
        #pragma unroll
        for (int nt = 0; nt < 4; nt++) {
            #pragma unroll
            for (int mt = 0; mt < 2; mt++) {
                const f2 p0 = max2z((f2){acc3[nt][mt][0], acc3[nt][mt][1]} + ga[nt][0]);
                const f2 p1 = max2z((f2){acc3[nt][mt][2], acc3[nt][mt][3]} + ga[nt][1]);
                uint2 d;
                d.x = pack2bf(p0.x, p0.y);
                d.y = pack2bf(p1.x, p1.y);
                *(uint2*)&myE[(nfr + 16 * mt) * 72 + 16 * nt + 4 * quad] = d;
            }
        }
        // --- GEMM4: rgb^T = V2^T(A) x g(B); rows = channels, col = sample ---
        f32x4 acc4[2];
        acc4[0] = (f32x4){0.0f, 0.0f, 0.0f, 0.0f};
        acc4[1] = (f32x4){0.0f, 0.0f, 0.0f, 0.0f};
        {
            short8 agg[2][2];
            #pragma unroll
            for (int mt = 0; mt < 2; mt++)
                #pragma unroll
                for (int kt = 0; kt < 2; kt++)
                    agg[mt][kt] = *(const short8*)&myE[(nfr + 16 * mt) * 72 + quad * 8 + kt * 32];
            #pragma unroll
            for (int mt = 0; mt < 2; mt++)
                #pragma unroll
                for (int kt = 0; kt < 2; kt++)
                    acc4[mt] = __builtin_amdgcn_mfma_f32_16x16x32_bf16(
                        v2f[kt], agg[mt][kt], acc4[mt], 0, 0, 0);
        }
        if (quad == 0) {
            #pragma unroll
            for (int mt = 0; mt < 2; mt++) {
                const int s = qq * 32 + nfr + 16 * mt;
                stbf(&sRgb[wave * 384 + s * 3 + 0],
                     1.0f / (1.0f + __expf(-(acc4[mt][0] + c20))));
                stbf(&sRgb[wave * 384 + s * 3 + 1],
                     1.0f / (1.0f + __expf(-(acc4[mt][1] + c21))));
                stbf(&sRgb[wave * 384 + s * 3 + 2],
                     1.0f / (1.0f + __expf(-(acc4[mt][2] + c22))));
            }
        }
    }

    // ---- exclusive multiplicative scan + weighted reduce (per wave) ----
    const float om0 = sOm[wave * 128 + 2 * lane];
    const float om1 = sOm[wave * 128 + 2 * lane + 1];
    const float al0 = 1.0f - om0;
    const float al1 = 1.0f - om1;

    float inc = om0 * om1;
    #pragma unroll
    for (int off = 1; off < 64; off <<= 1) {
        const float q = __shfl_up(inc, off, 64);
        if (lane >= off) inc *= q;
    }
    float Texc = __shfl_up(inc, 1, 64);
    if (lane == 0) Texc = 1.0f;

    const float T0 = Texc;
    const float T1 = Texc * om0;
    const float a0 = (T0 > 1e-4f) ? 1.0f : 0.0f;
    const float a1 = (T1 > 1e-4f) ? 1.0f : 0.0f;
    const float w0 = T0 * al0 * a0;
    const float w1 = T1 * al1 * a1;

    float cr = w0 * bf2f(sRgb[wave * 384 + (2 * lane) * 3 + 0]) +
               w1 * bf2f(sRgb[wave * 384 + (2 * lane + 1) * 3 + 0]);
    float cg = w0 * bf2f(sRgb[wave * 384 + (2 * lane) * 3 + 1]) +
               w1 * bf2f(sRgb[wave * 384 + (2 * lane + 1) * 3 + 1]);
    float cb = w0 * bf2f(sRgb[wave * 384 + (2 * lane) * 3 + 2]) +
               w1 * bf2f(sRgb[wave * 384 + (2 * lane + 1) * 3 + 2]);
    float tp = (a0 > 0.0f ? om0 : 1.0f) * (a1 > 0.0f ? om1 : 1.0f);

    #pragma unroll
    for (int off = 32; off > 0; off >>= 1) {
        cr += __shfl_xor(cr, off, 64);
        cg += __shfl_xor(cg, off, 64);
        cb += __shfl_xor(cb, off, 64);
        tp *= __shfl_xor(tp, off, 64);
    }

    if (lane == 0) {
        out[ray * 3 + 0] = cr;
        out[ray * 3 + 1] = cg;
        out[ray * 3 + 2] = cb;
        out[NRAYS * 3 + ray] = tp;
    }
}

extern "C" void kernel_launch(void* const* d_in, const int* in_sizes, int n_in,
                              void* d_out, int out_size, void* d_ws, size_t ws_size,
                              hipStream_t stream) {
    const float* orig = (const float*)d_in[0];
    const float* dirs = (const float*)d_in[1];
    const float* tmin = (const float*)d_in[2];
    const float* tmax = (const float*)d_in[3];
    const float* W1   = (const float*)d_in[4];
    const float* b1   = (const float*)d_in[5];
    const float* W2   = (const float*)d_in[6];
    const float* b2   = (const float*)d_in[7];
    const float* V1   = (const float*)d_in[8];
    const float* c1   = (const float*)d_in[9];
    const float* V2   = (const float*)d_in[10];
    const float* c2   = (const float*)d_in[11];

    march_kernel<<<NRAYS / 4, 256, 0, stream>>>(orig, dirs, tmin, tmax,
                                                W1, b1, W2, b2, V1, c1, V2, c2,
                                                (float*)d_out);
}